// Round 5
// baseline (118.971 us; speedup 1.0000x reference)
//
#include <hip/hip_runtime.h>
#include <math.h>

// Problem constants: B=2, T=15, H=W=192, C=P=16
#define HW_TOT 36864      // 192*192
#define T_LEN  15
#define NBLK   576        // 2 sequences per thread, 64 threads/block

// raw[] LDS offsets (floats)
#define R_WIN   0
#define R_BIN   16
#define R_AG    32
#define R_AB    48
#define R_LRE   64
#define R_LIM   80
#define R_LS    96
#define R_DV    112
#define R_FFG   128
#define R_FFB   144
#define R_OG    160
#define R_OB    176
#define R_BOUT  192
#define R_BRE   208   // 256
#define R_BIM   464   // 256
#define R_CRE   720   // 256
#define R_CIM   976   // 256
#define R_WENC  1232  // 512
#define R_WDEC  1744  // 256
#define R_WOUT  2000  // 256
#define R_N     2256

__device__ __forceinline__ float gelu_exact(float x){
  float ax = fabsf(x) * 0.7071067811865476f;
  float t  = 1.0f / (1.0f + 0.3275911f * ax);
  float poly = t*(0.254829592f + t*(-0.284496736f + t*(1.421413741f +
               t*(-1.453152027f + t*1.061405429f))));
  float er = 1.0f - poly * __expf(-ax*ax);
  er = copysignf(er, x);
  return 0.5f * x * (1.0f + er);
}

__global__ void __launch_bounds__(64) ssm_fused(
    const float* __restrict__ x,
    const float* __restrict__ w_in, const float* __restrict__ b_in,
    const float* __restrict__ ag,   const float* __restrict__ ab,
    const float* __restrict__ Lre,  const float* __restrict__ Lim,
    const float* __restrict__ Bre,  const float* __restrict__ Bim,
    const float* __restrict__ Cre,  const float* __restrict__ Cim,
    const float* __restrict__ Dv,   const float* __restrict__ ls,
    const float* __restrict__ ffg,  const float* __restrict__ ffb,
    const float* __restrict__ Wenc, const float* __restrict__ Wdec,
    const float* __restrict__ og,   const float* __restrict__ ob,
    const float* __restrict__ Wout, const float* __restrict__ bout,
    float* __restrict__ out)
{
  __shared__ float raw[R_N];
  __shared__ float cmr[256], cmi[256];
  __shared__ float U1r[240], U1i[240], U2r[240], U2i[240];
  __shared__ float Qr[16], Qi[16];
  __shared__ float G12[512];     // [c*32 + 2t] = G1[c,t], +1 = G2[c,t]
  __shared__ float G3[16];
  __shared__ float F123[48];     // F1 | F2 | F3

  const int tid = threadIdx.x;

  // ---- issue x loads first (HBM latency hidden under setup compute) ----
  const int n0 = blockIdx.x * 128 + tid;
  const int n1 = n0 + 64;
  const int b0 = (n0 >= HW_TOT) ? 1 : 0;
  const int b1 = (n1 >= HW_TOT) ? 1 : 0;
  const int r0 = n0 - b0 * HW_TOT;
  const int r1 = n1 - b1 * HW_TOT;
  const float* xp0 = x + (size_t)b0 * (T_LEN * HW_TOT) + r0;
  const float* xp1 = x + (size_t)b1 * (T_LEN * HW_TOT) + r1;
  float xv[2][T_LEN];
#pragma unroll
  for (int t = 0; t < T_LEN; ++t){
    xv[0][t] = xp0[(size_t)t * HW_TOT];
    xv[1][t] = xp1[(size_t)t * HW_TOT];
  }

  // ---- stage raw params into LDS (L2-hot broadcast across blocks) ----
  if (tid < 16){
    raw[R_WIN +tid] = w_in[tid];  raw[R_BIN +tid] = b_in[tid];
    raw[R_AG  +tid] = ag[tid];    raw[R_AB  +tid] = ab[tid];
    raw[R_LRE +tid] = Lre[tid];   raw[R_LIM +tid] = Lim[tid];
    raw[R_LS  +tid] = ls[tid];    raw[R_DV  +tid] = Dv[tid];
    raw[R_FFG +tid] = ffg[tid];   raw[R_FFB +tid] = ffb[tid];
    raw[R_OG  +tid] = og[tid];    raw[R_OB  +tid] = ob[tid];
    raw[R_BOUT+tid] = bout[tid];
  }
  for (int k = tid; k < 256; k += 64){
    raw[R_BRE+k] = Bre[k]; raw[R_BIM+k] = Bim[k];
    raw[R_CRE+k] = Cre[k]; raw[R_CIM+k] = Cim[k];
  }
  for (int k = tid; k < 512; k += 64) raw[R_WENC+k] = Wenc[k];
  for (int k = tid; k < 256; k += 64){
    raw[R_WDEC+k] = Wdec[k]; raw[R_WOUT+k] = Wout[k];
  }
  __syncthreads();

  // ---- per-thread redundant scalar stats ----
  float mw = 0.f, mb = 0.f;
#pragma unroll
  for (int c = 0; c < 16; ++c){ mw += raw[R_WIN+c]; mb += raw[R_BIN+c]; }
  mw *= 0.0625f; mb *= 0.0625f;
  float Saa = 0.f, Sad = 0.f, Sdd = 0.f;
#pragma unroll
  for (int c = 0; c < 16; ++c){
    float a = raw[R_WIN+c]-mw, d = raw[R_BIN+c]-mb;
    Saa = fmaf(a,a,Saa); Sad = fmaf(a,d,Sad); Sdd = fmaf(d,d,Sdd);
  }
  Saa *= 0.0625f; Sdd *= 0.0625f;
  const float Sad2 = 2.f * Sad * 0.0625f;

  // ---- lanes 0-15: per-p complex setup ----
  if (tid < 16){
    const int p = tid;
    { // F-vectors (indexed by c = tid)
      float a = raw[R_WIN+p]-mw, d = raw[R_BIN+p]-mb, g = raw[R_AG+p];
      F123[p]    = a*g;
      F123[16+p] = d*g;
      F123[32+p] = raw[R_AB+p];
    }
    float step = expf(raw[R_LS+p]);
    float lr = raw[R_LRE+p], li = raw[R_LIM+p];
    float er = expf(lr*step);
    float th = li*step;
    float Lbr = er*cosf(th), Lbi = er*sinf(th);   // Lam_bar
    float inv = 1.f/(lr*lr + li*li);
    float gr = Lbr - 1.f, gi = Lbi;
    float fr = (gr*lr + gi*li)*inv;
    float fi = (gi*lr - gr*li)*inv;
    float P1r=0,P1i=0,P2r=0,P2i=0,P3r=0,P3i=0;
    for (int c = 0; c < 16; ++c){
      float br = raw[R_BRE+p*16+c], bi = raw[R_BIM+p*16+c];
      float Bbr = fr*br - fi*bi, Bbi = fr*bi + fi*br;   // B_bar[p][c]
      float a = raw[R_WIN+c]-mw, d = raw[R_BIN+c]-mb, g = raw[R_AG+c];
      float f1 = a*g, f2 = d*g, f3 = raw[R_AB+c];
      P1r = fmaf(f1,Bbr,P1r); P1i = fmaf(f1,Bbi,P1i);
      P2r = fmaf(f2,Bbr,P2r); P2i = fmaf(f2,Bbi,P2i);
      P3r = fmaf(f3,Bbr,P3r); P3i = fmaf(f3,Bbi,P3i);
    }
    // powers: U1[p][j] = Lam_bar^j * P1, U2 likewise; K = sum_j Lam_bar^j
    float c1r=P1r, c1i=P1i, c2r=P2r, c2i=P2i;
    U1r[p*15+0]=c1r; U1i[p*15+0]=c1i;
    U2r[p*15+0]=c2r; U2i[p*15+0]=c2i;
    float kr=1.f, ki=0.f, pr=1.f, pi=0.f;
    for (int j = 1; j < T_LEN; ++j){
      float t1r = c1r*Lbr - c1i*Lbi, t1i = c1r*Lbi + c1i*Lbr;
      c1r=t1r; c1i=t1i;
      U1r[p*15+j]=c1r; U1i[p*15+j]=c1i;
      float t2r = c2r*Lbr - c2i*Lbi, t2i = c2r*Lbi + c2i*Lbr;
      c2r=t2r; c2i=t2i;
      U2r[p*15+j]=c2r; U2i[p*15+j]=c2i;
      float tpr = pr*Lbr - pi*Lbi, tpi = pr*Lbi + pi*Lbr;
      pr=tpr; pi=tpi;
      kr += pr; ki += pi;
    }
    Qr[p] = P3r*kr - P3i*ki;
    Qi[p] = P3r*ki + P3i*kr;
  }

  // ---- masked Cm (all lanes) ----
  for (int k = tid; k < 256; k += 64){
    int p = k & 15;
    float step = expf(raw[R_LS+p]);
    float freq = step * fabsf(raw[R_LIM+p]) * 0.15915494309189535f;
    float m = (freq < 0.25f) ? 1.f : 0.f;
    cmr[k] = raw[R_CRE+k]*m;
    cmi[k] = raw[R_CIM+k]*m;
  }
  __syncthreads();

  // ---- G matrices: G1[c,t] = Re(Cm[c,:] . U1[:,14-t]) ----
  for (int idx = tid; idx < 240; idx += 64){
    int c = idx / 15, t = idx - 15*c, j = 14 - t;
    float g1 = 0.f, g2 = 0.f;
    for (int p = 0; p < 16; ++p){
      float cr = cmr[c*16+p], ci = cmi[c*16+p];
      g1 = fmaf(cr, U1r[p*15+j], fmaf(-ci, U1i[p*15+j], g1));
      g2 = fmaf(cr, U2r[p*15+j], fmaf(-ci, U2i[p*15+j], g2));
    }
    G12[c*32 + 2*t    ] = g1;
    G12[c*32 + 2*t + 1] = g2;
  }
  if (tid < 16){
    int c = tid;
    float g3 = 0.f;
    for (int p = 0; p < 16; ++p)
      g3 = fmaf(cmr[c*16+p], Qr[p], fmaf(-cmi[c*16+p], Qi[p], g3));
    G3[c] = g3;
  }
  __syncthreads();

  // ======== main per-sequence compute (2 seqs/thread) ========
  float s1v[2][T_LEN], rsv[2][T_LEN];
#pragma unroll
  for (int s = 0; s < 2; ++s)
#pragma unroll
    for (int t = 0; t < T_LEN; ++t){
      float xt   = xv[s][t];
      float var  = fmaf(xt, fmaf(xt, Saa, Sad2), Sdd);
      float rstd = rsqrtf(var + 1e-5f);
      rsv[s][t] = rstd;
      s1v[s][t] = rstd * xt;
    }

  // y_c = G3_c + sum_t (s1_t*G1[c,t] + rstd_t*G2[c,t])
  float z[2][16];
#pragma unroll
  for (int c = 0; c < 16; ++c){
    float a0 = G3[c], a1 = a0;
#pragma unroll
    for (int t = 0; t < T_LEN; ++t){
      float g1 = G12[c*32 + 2*t];
      float g2 = G12[c*32 + 2*t + 1];
      a0 = fmaf(s1v[0][t], g1, fmaf(rsv[0][t], g2, a0));
      a1 = fmaf(s1v[1][t], g1, fmaf(rsv[1][t], g2, a1));
    }
    z[0][c] = a0; z[1][c] = a1;
  }

  // fx at t=T-1, then z = gelu(y + fx*D) + fx
  float fx2[2][16];
#pragma unroll
  for (int s = 0; s < 2; ++s){
    const float s1L = s1v[s][T_LEN-1], rsL = rsv[s][T_LEN-1];
#pragma unroll
    for (int c = 0; c < 16; ++c){
      float f = fmaf(s1L, F123[c], fmaf(rsL, F123[16+c], F123[32+c]));
      float y = fmaf(f, raw[R_DV+c], z[s][c]);
      z[s][c] = gelu_exact(y) + f;
    }
    // LN(z) -> fx2
    float mu = 0.f;
#pragma unroll
    for (int c = 0; c < 16; ++c) mu += z[s][c];
    mu *= 0.0625f;
    float vr = 0.f;
#pragma unroll
    for (int c = 0; c < 16; ++c){ float d = z[s][c]-mu; vr = fmaf(d,d,vr); }
    vr *= 0.0625f;
    float rs = rsqrtf(vr + 1e-5f);
#pragma unroll
    for (int c = 0; c < 16; ++c)
      fx2[s][c] = fmaf((z[s][c]-mu)*rs, raw[R_FFG+c], raw[R_FFB+c]);
  }

  // enc = fx2 @ Wenc^T ; h = a * gelu(g)
  float hg[2][16];
#pragma unroll
  for (int c = 0; c < 16; ++c){
    float a0=0.f, g0=0.f, a1=0.f, g1=0.f;
#pragma unroll
    for (int k = 0; k < 16; ++k){
      float wa = raw[R_WENC + c*16 + k];
      float wg = raw[R_WENC + (16+c)*16 + k];
      a0 = fmaf(fx2[0][k], wa, a0); g0 = fmaf(fx2[0][k], wg, g0);
      a1 = fmaf(fx2[1][k], wa, a1); g1 = fmaf(fx2[1][k], wg, g1);
    }
    hg[0][c] = a0 * gelu_exact(g0);
    hg[1][c] = a1 * gelu_exact(g1);
  }

  // z2 = hg @ Wdec^T + fx2
  float z2[2][16];
#pragma unroll
  for (int c = 0; c < 16; ++c){
    float acc0 = fx2[0][c], acc1 = fx2[1][c];
#pragma unroll
    for (int k = 0; k < 16; ++k){
      float wd = raw[R_WDEC + c*16 + k];
      acc0 = fmaf(hg[0][k], wd, acc0);
      acc1 = fmaf(hg[1][k], wd, acc1);
    }
    z2[0][c] = acc0; z2[1][c] = acc1;
  }

  // final LN -> qv
  float qv[2][16];
#pragma unroll
  for (int s = 0; s < 2; ++s){
    float mu = 0.f;
#pragma unroll
    for (int c = 0; c < 16; ++c) mu += z2[s][c];
    mu *= 0.0625f;
    float vr = 0.f;
#pragma unroll
    for (int c = 0; c < 16; ++c){ float d = z2[s][c]-mu; vr = fmaf(d,d,vr); }
    vr *= 0.0625f;
    float rs = rsqrtf(vr + 1e-5f);
#pragma unroll
    for (int c = 0; c < 16; ++c)
      qv[s][c] = fmaf((z2[s][c]-mu)*rs, raw[R_OG+c], raw[R_OB+c]);
  }

  // out head + store (16 coalesced planes per seq)
  float* op0 = out + (size_t)b0 * (16*HW_TOT) + r0;
  float* op1 = out + (size_t)b1 * (16*HW_TOT) + r1;
#pragma unroll
  for (int c = 0; c < 16; ++c){
    float acc0 = raw[R_BOUT+c], acc1 = acc0;
#pragma unroll
    for (int k = 0; k < 16; ++k){
      float wo = raw[R_WOUT + c*16 + k];
      acc0 = fmaf(qv[0][k], wo, acc0);
      acc1 = fmaf(qv[1][k], wo, acc1);
    }
    op0[(size_t)c * HW_TOT] = acc0;
    op1[(size_t)c * HW_TOT] = acc1;
  }
}

extern "C" void kernel_launch(void* const* d_in, const int* in_sizes, int n_in,
                              void* d_out, int out_size, void* d_ws, size_t ws_size,
                              hipStream_t stream)
{
  const float* x    = (const float*)d_in[0];
  const float* w_in = (const float*)d_in[1];
  const float* b_in = (const float*)d_in[2];
  const float* ag   = (const float*)d_in[3];
  const float* ab   = (const float*)d_in[4];
  const float* Lre  = (const float*)d_in[5];
  const float* Lim  = (const float*)d_in[6];
  const float* Bre  = (const float*)d_in[7];
  const float* Bim  = (const float*)d_in[8];
  const float* Cre  = (const float*)d_in[9];
  const float* Cim  = (const float*)d_in[10];
  const float* Dv   = (const float*)d_in[11];
  const float* ls   = (const float*)d_in[12];
  const float* ffg  = (const float*)d_in[13];
  const float* ffb  = (const float*)d_in[14];
  const float* Wenc = (const float*)d_in[15];
  const float* Wdec = (const float*)d_in[16];
  const float* og   = (const float*)d_in[17];
  const float* ob   = (const float*)d_in[18];
  const float* Wout = (const float*)d_in[19];
  const float* bout = (const float*)d_in[20];
  float* out = (float*)d_out;

  ssm_fused<<<NBLK, 64, 0, stream>>>(x, w_in, b_in, ag, ab, Lre, Lim,
                                     Bre, Bim, Cre, Cim, Dv, ls, ffg, ffb,
                                     Wenc, Wdec, og, ob, Wout, bout, out);
}